// Round 19
// baseline (91.377 us; speedup 1.0000x reference)
//
#include <hip/hip_runtime.h>
#include <math.h>

#define B_ 64
#define L_ 512
#define N_ 321
#define P_ 720
#define E_ 8
#define R_ 32
#define CID_ 32
#define H_ 64
#define ER_ 256
#define KB2 288      // ER_ + 8 bias-rank + 1 mean + 23 zero-pad
#define HGROWS 384   // 6 n-tiles x 64 (rows >= N_ hold dup/junk, never used)

typedef __attribute__((ext_vector_type(8))) short bf16x8;
typedef __attribute__((ext_vector_type(4))) float f32x4;
typedef __attribute__((ext_vector_type(8))) unsigned short u16x8;
typedef __attribute__((ext_vector_type(4))) unsigned short u16x4;

// workspace layout (float offsets)
#define OFF_GATE 0                        // 2568
#define OFF_CS1  2568                     // 256
#define OFF_W1K  2824                     // bf16 256*512 = 65536 f
#define OFF_W2X  68360                    // bf16 720*288 = 103680 f
#define OFF_HG   172040                   // bf16 64*384*288 = 3538944 f
// total ~14.8 MB

__device__ __forceinline__ unsigned short f2bf(float f) {
    unsigned u = __float_as_uint(f);
    u += 0x7fffu + ((u >> 16) & 1u);
    return (unsigned short)(u >> 16);
}
__device__ __forceinline__ float bf2f(unsigned short h) {
    return __uint_as_float(((unsigned)h) << 16);
}

// ---------------- prep: w1k, w2x, cs1, router (merged) ----------------------
__global__ void prep_kernel(const float* __restrict__ w1, const float* __restrict__ w2,
                            const float* __restrict__ bias,
                            const float* __restrict__ ident,
                            const float* __restrict__ rw1, const float* __restrict__ rb1,
                            const float* __restrict__ rw2, const float* __restrict__ rb2,
                            unsigned short* __restrict__ w1k, unsigned short* __restrict__ w2x,
                            float* __restrict__ cs1, float* __restrict__ gate) {
    __shared__ float red[16][32];
    __shared__ float hid[H_];
    __shared__ float lg[E_];
    int bid = blockIdx.x, t = threadIdx.x;
    if (bid < 128) {                  // w1k [er][l]: 256*512 elems, 512 thr x 2
        #pragma unroll
        for (int r = 0; r < 2; ++r) {
            int g = bid*1024 + r*512 + t;
            int er = g >> 9, l = g & 511;
            w1k[g] = f2bf(w1[(size_t)(er >> 5)*(L_*R_) + (size_t)l*R_ + (er & 31)]);
        }
    } else if (bid < 848) {           // w2x row p: K-extended
        int p = bid - 128;
        if (t < KB2) {
            unsigned short v;
            if (t < ER_)            v = f2bf(w2[(size_t)t*P_ + p]);
            else if (t < ER_ + E_)  v = f2bf(bias[(size_t)(t - ER_)*P_ + p]);
            else if (t == ER_ + E_) v = 0x3f80;  // bf16(1.0) for the mean lane
            else                    v = 0;
            w2x[(size_t)p*KB2 + t] = v;
        }
    } else if (bid < 856) {           // cs1: 8 blocks, one expert each (512 thr)
        int e = bid - 848;
        int q = t >> 5, r = t & 31;
        float s = 0.f;
        for (int l = q; l < L_; l += 16)
            s += bf2f(f2bf(w1[(size_t)e*(L_*R_) + (size_t)l*R_ + r]));
        red[q][r] = s;
        __syncthreads();
        if (q == 0) {
            #pragma unroll
            for (int qq = 1; qq < 16; ++qq) s += red[qq][r];
            cs1[e*32 + r] = s;
        }
    } else {                          // router: one n per block (t<64 active)
        int n = bid - 856;
        if (t < H_) {
            float acc = rb1[t];
            #pragma unroll
            for (int c = 0; c < CID_; ++c)
                acc = fmaf(ident[n*CID_ + c], rw1[c*H_ + t], acc);
            hid[t] = fmaxf(acc, 0.f);
        }
        __syncthreads();
        if (t < E_) {
            float a = rb2[t];
            #pragma unroll
            for (int h = 0; h < H_; ++h) a = fmaf(hid[h], rw2[h*E_ + t], a);
            lg[t] = a;
        }
        __syncthreads();
        if (t == 0) {
            float m = lg[0];
            #pragma unroll
            for (int e = 1; e < E_; ++e) m = fmaxf(m, lg[e]);
            float s = 0.f, ex[E_];
            #pragma unroll
            for (int e = 0; e < E_; ++e) { ex[e] = expf(lg[e] - m); s += ex[e]; }
            float inv = 1.f / s;
            #pragma unroll
            for (int e = 0; e < E_; ++e) gate[n*E_ + e] = ex[e] * inv;
        }
    }
}

// ---------------- GEMM1: max-occupancy (8 blocks/CU, 32 waves/CU) -----------
// grid 1536 = 8 xcd * (8 b * 6 nt * 4 eq), 256 thr (4 waves), 19 KB LDS.
// Wave owns 16er x 64n; 8 rounds of K=64 ping-pong; fused f32 stats;
// epilogue gate*(acc - mean*cs1); K-ext by eq==3. All 4 eq-blocks of a
// (b,nt) land on one XCD -> x slice HBM-read once, L2-served 3x.
__global__ __launch_bounds__(256, 8) void gemm1_kernel(
        const float* __restrict__ x, const unsigned short* __restrict__ w1k,
        const float* __restrict__ gate, const float* __restrict__ cs1,
        unsigned short* __restrict__ hg) {
    __shared__ unsigned short buf[2][64][64];    // 16384 B, XOR-swizzled rows
    __shared__ float red1[4][64], red2[4][64];   // 2048 B
    __shared__ float meanS[64], sdS[64];

    const int bid = blockIdx.x;
    const int xcd = bid & 7;
    const int slot = bid >> 3;           // 0..191
    const int b   = xcd + ((slot / 24) << 3);
    const int rem = slot % 24;
    const int nt  = rem >> 2;            // 0..5
    const int eq  = rem & 3;             // er-quarter
    const int n0  = nt * 64;
    const int m0  = eq * 64;

    const int tid  = threadIdx.x;
    const int lane = tid & 63;
    const int wave = tid >> 6;          // 0..3
    const int l15  = lane & 15;
    const int kgrp = lane >> 4;         // 0..3

    // staging role: thread = (xn, wave): 16 k per round (wave covers k 16*wave..+16)
    const int xn  = lane;
    const int gn  = n0 + xn;
    const int gnc = (gn < N_) ? gn : (N_ - 1);
    const float* xp = x + (size_t)b*L_*N_ + gnc;
    const int swz = (xn & 7) << 4;       // byte-XOR within 128 B row
    char* myrow0 = (char*)&buf[0][xn][0];
    char* myrow1 = (char*)&buf[1][xn][0];

    // MFMA roles: wave owns er rows m0 + wave*16 .. +16
    const unsigned short* apA = w1k + (size_t)(m0 + wave*16 + l15)*L_;
    const int rsw = (l15 & 7) << 4;

    float s1 = 0.f, s2 = 0.f;
    float v[16];
    f32x4 acc[4];
    #pragma unroll
    for (int j = 0; j < 4; ++j) acc[j] = (f32x4){0.f,0.f,0.f,0.f};

#define LOADV(rd_) {                                                            \
    const int kb = (rd_)*64 + wave*16;                                          \
    _Pragma("unroll")                                                           \
    for (int i_ = 0; i_ < 16; ++i_)                                             \
        v[i_] = xp[(size_t)(kb + i_)*N_]; }
#define STOREV(rd_) {                                                           \
    char* dst = ((rd_) & 1) ? myrow1 : myrow0;                                  \
    u16x8 pk0, pk1;                                                             \
    _Pragma("unroll")                                                           \
    for (int i_ = 0; i_ < 8; ++i_) {                                            \
        s1 += v[i_]; s2 = fmaf(v[i_], v[i_], s2); pk0[i_] = f2bf(v[i_]); }      \
    _Pragma("unroll")                                                           \
    for (int i_ = 0; i_ < 8; ++i_) {                                            \
        float f_ = v[8+i_];                                                     \
        s1 += f_; s2 = fmaf(f_, f_, s2); pk1[i_] = f2bf(f_); }                  \
    *(u16x8*)(dst + ((wave*32)      ^ swz)) = pk0;                              \
    *(u16x8*)(dst + ((wave*32 + 16) ^ swz)) = pk1; }

    LOADV(0);
    STOREV(0);
    __syncthreads();

    // A-fragment ring: 4 slots, prefetch distance 2 (kk = 32-k chunk, 16 total)
    bf16x8 af[4];
#define LDA(s_, kk_) af[s_] = *(const bf16x8*)&apA[(kk_)*32 + kgrp*8];
    LDA(0, 0); LDA(1, 1);

    #pragma unroll
    for (int rd = 0; rd < 8; ++rd) {
        if (rd < 7) LOADV(rd + 1);          // global loads hide under MFMA
        const unsigned short (*cb)[64] = buf[rd & 1];
        #pragma unroll
        for (int ks = 0; ks < 2; ++ks) {
            const int kk = rd*2 + ks;
            if (kk + 2 < 16) LDA((kk + 2) & 3, kk + 2);
            const int cbyte = ks*64 + kgrp*16;
            bf16x8 bfr[4];
            #pragma unroll
            for (int fn = 0; fn < 4; ++fn)
                bfr[fn] = *(const bf16x8*)((const char*)&cb[fn*16 + l15][0] + (cbyte ^ rsw));
            #pragma unroll
            for (int fn = 0; fn < 4; ++fn)
                acc[fn] = __builtin_amdgcn_mfma_f32_16x16x32_bf16(af[kk & 3], bfr[fn], acc[fn], 0, 0, 0);
        }
        if (rd < 7) STOREV(rd + 1);
        __syncthreads();
    }
#undef LDA
#undef LOADV
#undef STOREV

    // ---- stats reduce (f32-exact; accumulated during staging) ----
    red1[wave][xn] = s1;
    red2[wave][xn] = s2;
    __syncthreads();
    if (tid < 64) {
        float a = 0.f, qq = 0.f;
        #pragma unroll
        for (int kk = 0; kk < 4; ++kk) { a += red1[kk][tid]; qq += red2[kk][tid]; }
        float mean = a * (1.f/L_);
        float var = (qq - (float)L_*mean*mean) * (1.f/(L_-1));
        var = fmaxf(var, 0.f);
        meanS[tid] = mean;
        sdS[tid]   = sqrtf(var) + 1e-6f;
    }
    __syncthreads();

    // ---- epilogue: hg[b][n0+nl][m0..m0+64) = gate*(acc - mean*cs1) ----
    unsigned short* hgb = hg + ((size_t)b * HGROWS + n0) * KB2;
    {
        int er0 = m0 + wave*16 + kgrp*4;
        int e = er0 >> 5;
        f32x4 c4 = *(const f32x4*)&cs1[er0];
        #pragma unroll
        for (int fn = 0; fn < 4; ++fn) {
            int nl = fn*16 + l15;
            int gnn = n0 + nl; if (gnn > N_-1) gnn = N_-1;
            float g = gate[gnn*E_ + e];
            float m = meanS[nl];
            u16x4 pk;
            #pragma unroll
            for (int j = 0; j < 4; ++j)
                pk[j] = f2bf(g * (acc[fn][j] - m * c4[j]));
            *(u16x4*)&hgb[(size_t)nl*KB2 + er0] = pk;
        }
    }
    if (eq == 3) {   // K-extension cols 256..287: 64 rows x 8 segs, 256 thr x2
        int nl = tid >> 2, s4 = tid & 3;
        int gnn = n0 + nl; if (gnn > N_-1) gnn = N_-1;
        float sd = sdS[nl], m = meanS[nl];
        #pragma unroll
        for (int half = 0; half < 2; ++half) {
            int seg = s4 + half*4;
            u16x4 pk;
            #pragma unroll
            for (int jj = 0; jj < 4; ++jj) {
                int k = seg*4 + jj;
                float vv = (k < E_) ? gate[gnn*E_ + k] * sd : ((k == E_) ? m : 0.f);
                pk[jj] = f2bf(vv);
            }
            *(u16x4*)&hgb[(size_t)nl*KB2 + ER_ + seg*4] = pk;
        }
    }
}

// ---------------- GEMM2: out = w2x . hg^T, one LDS stage + barrier ----------
// grid 2304 = 8 xcd * (8 b * (6 pt * 6 nt)); BM=128 p, BN=64 n, K=288.
#define HGS 296   // u16 LDS stride (148 dw -> 2-way aliasing, free)
__global__ __launch_bounds__(512, 6) void gemm2_kernel(
        const unsigned short* __restrict__ hg, const unsigned short* __restrict__ w2x,
        float* __restrict__ out) {
    __shared__ __align__(16) char smem[64 * HGS * 2];      // 37888 B
    unsigned short* hgL = (unsigned short*)smem;           // [64][296]
    const int bid = blockIdx.x;
    const int xcd = bid & 7;
    const int idx = bid >> 3;            // 0..287
    const int b   = (xcd << 3) + idx / 36;
    const int rem = idx % 36;
    const int p0  = (rem / 6) * 128;
    const int n0  = (rem % 6) * 64;

    const int tid  = threadIdx.x;
    const int lane = tid & 63;
    const int wave = tid >> 6;
    const int l15  = lane & 15;
    const int kgrp = lane >> 4;

    // stage hg tile [64][288] -> LDS (16B chunks, 36 per row)
    const unsigned short* hgb = hg + ((size_t)b * HGROWS + n0) * KB2;
    #pragma unroll
    for (int it = 0; it < 5; ++it) {
        int c = tid + it*512;
        if (c < 64*36) {
            int row = c / 36, col = c % 36;
            *(u16x8*)&hgL[(size_t)row*HGS + col*8] =
                *(const u16x8*)&hgb[(size_t)row*KB2 + col*8];
        }
    }
    __syncthreads();

    // K-loop: wave owns 16 p-rows; A-frags from L2-hot w2x, B-frags from LDS
    int prow = p0 + wave*16 + l15; if (prow > P_-1) prow = P_-1;
    const unsigned short* ap = w2x + (size_t)prow*KB2;
    f32x4 o[4];
    #pragma unroll
    for (int j = 0; j < 4; ++j) o[j] = (f32x4){0.f,0.f,0.f,0.f};
    #pragma unroll
    for (int ks = 0; ks < 9; ++ks) {
        bf16x8 afr = *(const bf16x8*)&ap[ks*32 + kgrp*8];
        #pragma unroll
        for (int fn = 0; fn < 4; ++fn) {
            bf16x8 bfr = *(const bf16x8*)&hgL[(size_t)(fn*16 + l15)*HGS + ks*32 + kgrp*8];
            o[fn] = __builtin_amdgcn_mfma_f32_16x16x32_bf16(afr, bfr, o[fn], 0, 0, 0);
        }
    }
    __syncthreads();   // all waves done reading hgL; patch may overwrite

    // patch-transpose: D rows p_loc = kgrp*4+j, cols n_loc = fn*16+l15
    float* patch = (float*)smem + wave * 1088;   // [16][68] f32 = 4352 B
    #pragma unroll
    for (int fn = 0; fn < 4; ++fn)
        #pragma unroll
        for (int j = 0; j < 4; ++j)
            patch[(kgrp*4 + j)*68 + fn*16 + l15] = o[fn][j];
    const int pw0 = p0 + wave*16;
    #pragma unroll
    for (int pass = 0; pass < 4; ++pass) {
        int ploc = pass*4 + kgrp;
        f32x4 v = *(const f32x4*)&patch[ploc*68 + l15*4];
        int p = pw0 + ploc;
        int n = n0 + l15*4;
        if (p < P_) {
            float* orow = out + ((size_t)b*P_ + p)*N_;
            if (n + 3 < N_) {
                *(f32x4*)&orow[n] = v;
            } else {
                #pragma unroll
                for (int j = 0; j < 4; ++j)
                    if (n + j < N_) orow[n + j] = v[j];
            }
        }
    }
}

extern "C" void kernel_launch(void* const* d_in, const int* in_sizes, int n_in,
                              void* d_out, int out_size, void* d_ws, size_t ws_size,
                              hipStream_t stream) {
    const float* x     = (const float*)d_in[0];
    const float* ident = (const float*)d_in[1];
    const float* rw1   = (const float*)d_in[2];
    const float* rb1   = (const float*)d_in[3];
    const float* rw2   = (const float*)d_in[4];
    const float* rb2   = (const float*)d_in[5];
    const float* w1    = (const float*)d_in[6];
    const float* w2    = (const float*)d_in[7];
    const float* bias  = (const float*)d_in[8];
    float* out = (float*)d_out;
    float* ws  = (float*)d_ws;

    float* gate = ws + OFF_GATE;
    float* cs1  = ws + OFF_CS1;
    unsigned short* w1k = (unsigned short*)(ws + OFF_W1K);
    unsigned short* w2x = (unsigned short*)(ws + OFF_W2X);
    unsigned short* hg  = (unsigned short*)(ws + OFF_HG);

    prep_kernel<<<856 + N_, 512, 0, stream>>>(w1, w2, bias, ident, rw1, rb1,
                                              rw2, rb2, w1k, w2x, cs1, gate);
    gemm1_kernel<<<dim3(1536), 256, 0, stream>>>(x, w1k, gate, cs1, hg);
    gemm2_kernel<<<dim3(2304), 512, 0, stream>>>(hg, w2x, out);
}

// Round 20
// 59.666 us; speedup vs baseline: 1.5315x; 1.5315x over previous
//
#include <hip/hip_runtime.h>
#include <math.h>

#define B_ 64
#define L_ 512
#define N_ 321
#define P_ 720
#define E_ 8
#define R_ 32
#define CID_ 32
#define H_ 64
#define ER_ 256
#define KB2 288      // ER_ + 8 bias-rank + 1 mean + 23 zero-pad
#define HGROWS 384   // 6 n-tiles x 64 (rows >= N_ hold dup/junk, never used)

typedef __attribute__((ext_vector_type(8))) short bf16x8;
typedef __attribute__((ext_vector_type(4))) float f32x4;
typedef __attribute__((ext_vector_type(8))) unsigned short u16x8;
typedef __attribute__((ext_vector_type(4))) unsigned short u16x4;

// workspace layout (float offsets)
#define OFF_GATE 0                        // 2568
#define OFF_CS1  2568                     // 256
#define OFF_W1K  2824                     // bf16 256*512 = 65536 f
#define OFF_W2X  68360                    // bf16 720*288 = 103680 f
#define OFF_HG   172040                   // bf16 64*384*288 = 3538944 f
// total ~14.8 MB

__device__ __forceinline__ unsigned short f2bf(float f) {
    unsigned u = __float_as_uint(f);
    u += 0x7fffu + ((u >> 16) & 1u);
    return (unsigned short)(u >> 16);
}
__device__ __forceinline__ float bf2f(unsigned short h) {
    return __uint_as_float(((unsigned)h) << 16);
}

// ---------------- prep: w1k, w2x, cs1, router (merged) ----------------------
__global__ void prep_kernel(const float* __restrict__ w1, const float* __restrict__ w2,
                            const float* __restrict__ bias,
                            const float* __restrict__ ident,
                            const float* __restrict__ rw1, const float* __restrict__ rb1,
                            const float* __restrict__ rw2, const float* __restrict__ rb2,
                            unsigned short* __restrict__ w1k, unsigned short* __restrict__ w2x,
                            float* __restrict__ cs1, float* __restrict__ gate) {
    __shared__ float red[16][32];
    __shared__ float hid[H_];
    __shared__ float lg[E_];
    int bid = blockIdx.x, t = threadIdx.x;
    if (bid < 128) {                  // w1k [er][l]: 256*512 elems, 512 thr x 2
        #pragma unroll
        for (int r = 0; r < 2; ++r) {
            int g = bid*1024 + r*512 + t;
            int er = g >> 9, l = g & 511;
            w1k[g] = f2bf(w1[(size_t)(er >> 5)*(L_*R_) + (size_t)l*R_ + (er & 31)]);
        }
    } else if (bid < 848) {           // w2x row p: K-extended
        int p = bid - 128;
        if (t < KB2) {
            unsigned short v;
            if (t < ER_)            v = f2bf(w2[(size_t)t*P_ + p]);
            else if (t < ER_ + E_)  v = f2bf(bias[(size_t)(t - ER_)*P_ + p]);
            else if (t == ER_ + E_) v = 0x3f80;  // bf16(1.0) for the mean lane
            else                    v = 0;
            w2x[(size_t)p*KB2 + t] = v;
        }
    } else if (bid < 856) {           // cs1: 8 blocks, one expert each (512 thr)
        int e = bid - 848;
        int q = t >> 5, r = t & 31;
        float s = 0.f;
        for (int l = q; l < L_; l += 16)
            s += bf2f(f2bf(w1[(size_t)e*(L_*R_) + (size_t)l*R_ + r]));
        red[q][r] = s;
        __syncthreads();
        if (q == 0) {
            #pragma unroll
            for (int qq = 1; qq < 16; ++qq) s += red[qq][r];
            cs1[e*32 + r] = s;
        }
    } else {                          // router: one n per block (t<64 active)
        int n = bid - 856;
        if (t < H_) {
            float acc = rb1[t];
            #pragma unroll
            for (int c = 0; c < CID_; ++c)
                acc = fmaf(ident[n*CID_ + c], rw1[c*H_ + t], acc);
            hid[t] = fmaxf(acc, 0.f);
        }
        __syncthreads();
        if (t < E_) {
            float a = rb2[t];
            #pragma unroll
            for (int h = 0; h < H_; ++h) a = fmaf(hid[h], rw2[h*E_ + t], a);
            lg[t] = a;
        }
        __syncthreads();
        if (t == 0) {
            float m = lg[0];
            #pragma unroll
            for (int e = 1; e < E_; ++e) m = fmaxf(m, lg[e]);
            float s = 0.f, ex[E_];
            #pragma unroll
            for (int e = 0; e < E_; ++e) { ex[e] = expf(lg[e] - m); s += ex[e]; }
            float inv = 1.f / s;
            #pragma unroll
            for (int e = 0; e < E_; ++e) gate[n*E_ + e] = ex[e] * inv;
        }
    }
}

// ---------------- GEMM1: depth-3 register prefetch ring (T4/T14) ------------
// grid 768 = 8 xcd * (8 b * 6 nt * 2 eq), 512 thr, (512,4) ~128 VGPR.
// Wave owns 16er x 64n; 16 rounds of K=32; x loads issued 3 rounds ahead
// (v[3][16] = 48 VGPR in flight) so ~3 round-times of MFMA/LDS cover the
// ~900cyc HBM latency. Fused f32 stats; epilogue gate*(acc - mean*cs1).
__global__ __launch_bounds__(512, 4) void gemm1_kernel(
        const float* __restrict__ x, const unsigned short* __restrict__ w1k,
        const float* __restrict__ gate, const float* __restrict__ cs1,
        unsigned short* __restrict__ hg) {
    __shared__ unsigned short buf[2][64][128];   // 32768 B, XOR-swizzled rows
    __shared__ float red1[8][64], red2[8][64];   // 4096 B
    __shared__ float meanS[64], sdS[64];

    const int bid = blockIdx.x;
    const int xcd = bid & 7;
    const int idx = bid >> 3;            // 0..95
    const int b   = (xcd << 3) + idx / 12;
    const int rem = idx % 12;
    const int nt  = rem >> 1;            // 0..5
    const int eq  = rem & 1;             // er-half
    const int n0  = nt * 64;
    const int m0  = eq * 128;

    const int tid  = threadIdx.x;
    const int lane = tid & 63;
    const int wave = tid >> 6;          // 0..7
    const int l15  = lane & 15;
    const int kgrp = lane >> 4;         // 0..3

    // staging role: thread = (xn, wave): 16 k per round (k-chunk = rd*128 + wave*16)
    const int xn  = lane;
    const int gn  = n0 + xn;
    const int gnc = (gn < N_) ? gn : (N_ - 1);
    const float* xp = x + (size_t)b*L_*N_ + gnc;
    const int swz = (xn & 7) << 4;       // byte-XOR for LDS row xn
    char* myrow0 = (char*)&buf[0][xn][0];
    char* myrow1 = (char*)&buf[1][xn][0];

    // MFMA roles: wave owns er rows m0 + wave*16 .. +16  (rounds of K=128)
    const unsigned short* apA = w1k + (size_t)(m0 + wave*16 + l15)*L_;
    const int rsw = (l15 & 7) << 4;

    float s1 = 0.f, s2 = 0.f;
    float v[3][16];                      // depth-3 prefetch ring (static idx)
    f32x4 acc[4];
    #pragma unroll
    for (int j = 0; j < 4; ++j) acc[j] = (f32x4){0.f,0.f,0.f,0.f};

#define LOADV(s_, rd_) {                                                        \
    const int kb = (rd_)*128 + wave*16;                                         \
    _Pragma("unroll")                                                           \
    for (int i_ = 0; i_ < 16; ++i_)                                             \
        v[s_][i_] = xp[(size_t)(kb + i_)*N_]; }
#define STOREV(s_, rd_) {                                                       \
    char* dst = ((rd_) & 1) ? myrow1 : myrow0;                                  \
    u16x8 pk0, pk1;                                                             \
    _Pragma("unroll")                                                           \
    for (int i_ = 0; i_ < 8; ++i_) {                                            \
        float f_ = v[s_][i_];                                                   \
        s1 += f_; s2 = fmaf(f_, f_, s2); pk0[i_] = f2bf(f_); }                  \
    _Pragma("unroll")                                                           \
    for (int i_ = 0; i_ < 8; ++i_) {                                            \
        float f_ = v[s_][8+i_];                                                 \
        s1 += f_; s2 = fmaf(f_, f_, s2); pk1[i_] = f2bf(f_); }                  \
    *(u16x8*)(dst + ((wave*32)      ^ swz)) = pk0;                              \
    *(u16x8*)(dst + ((wave*32 + 16) ^ swz)) = pk1; }

    // prologue: 3 rounds of loads in flight; round-0 tile staged
    LOADV(0, 0); LOADV(1, 1); LOADV(2, 2);
    STOREV(0, 0);
    __syncthreads();

    // A-fragment ring: 4 slots, prefetch distance 2 (kk = 32-k chunk index)
    bf16x8 af[4];
#define LDA(s_, kk_) af[s_] = *(const bf16x8*)&apA[(kk_)*32 + kgrp*8];
    LDA(0, 0); LDA(1, 1);

    // rounds are K=128 (4 kk each); 4 rounds total
    #pragma unroll
    for (int rd = 0; rd < 4; ++rd) {
        if (rd + 3 < 4) { LOADV(rd % 3, rd + 3); }   // only rd=0 fires (depth 3 of 4)
        const unsigned short (*cb)[128] = buf[rd & 1];
        #pragma unroll
        for (int ks = 0; ks < 4; ++ks) {
            const int kk = rd*4 + ks;
            if (kk + 2 < 16) LDA((kk + 2) & 3, kk + 2);
            const int cbyte = ks*64 + kgrp*16;
            bf16x8 bfr[4];
            #pragma unroll
            for (int fn = 0; fn < 4; ++fn)
                bfr[fn] = *(const bf16x8*)((const char*)&cb[fn*16 + l15][0] + (cbyte ^ rsw));
            #pragma unroll
            for (int fn = 0; fn < 4; ++fn)
                acc[fn] = __builtin_amdgcn_mfma_f32_16x16x32_bf16(af[kk & 3], bfr[fn], acc[fn], 0, 0, 0);
        }
        if (rd + 1 < 4) STOREV((rd + 1) % 3, rd + 1);
        __syncthreads();
    }
#undef LDA
#undef LOADV
#undef STOREV

    // ---- stats reduce (f32-exact; accumulated during staging) ----
    red1[wave][xn] = s1;
    red2[wave][xn] = s2;
    __syncthreads();
    if (tid < 64) {
        float a = 0.f, qq = 0.f;
        #pragma unroll
        for (int kk = 0; kk < 8; ++kk) { a += red1[kk][tid]; qq += red2[kk][tid]; }
        float mean = a * (1.f/L_);
        float var = (qq - (float)L_*mean*mean) * (1.f/(L_-1));
        var = fmaxf(var, 0.f);
        meanS[tid] = mean;
        sdS[tid]   = sqrtf(var) + 1e-6f;
    }
    __syncthreads();

    // ---- epilogue: hg[b][n0+nl][m0..m0+128) = gate*(acc - mean*cs1) ----
    unsigned short* hgb = hg + ((size_t)b * HGROWS + n0) * KB2;
    {
        int er0 = m0 + wave*16 + kgrp*4;
        int e = er0 >> 5;
        f32x4 c4 = *(const f32x4*)&cs1[er0];
        #pragma unroll
        for (int fn = 0; fn < 4; ++fn) {
            int nl = fn*16 + l15;
            int gnn = n0 + nl; if (gnn > N_-1) gnn = N_-1;
            float g = gate[gnn*E_ + e];
            float m = meanS[nl];
            u16x4 pk;
            #pragma unroll
            for (int j = 0; j < 4; ++j)
                pk[j] = f2bf(g * (acc[fn][j] - m * c4[j]));
            *(u16x4*)&hgb[(size_t)nl*KB2 + er0] = pk;
        }
    }
    if (eq == 1) {   // K-extension cols 256..287: 64 rows x 8 segs (512 thr)
        int nl = tid >> 3, seg = tid & 7;
        int gnn = n0 + nl; if (gnn > N_-1) gnn = N_-1;
        float sd = sdS[nl], m = meanS[nl];
        u16x4 pk;
        #pragma unroll
        for (int jj = 0; jj < 4; ++jj) {
            int k = seg*4 + jj;
            float vv = (k < E_) ? gate[gnn*E_ + k] * sd : ((k == E_) ? m : 0.f);
            pk[jj] = f2bf(vv);
        }
        *(u16x4*)&hgb[(size_t)nl*KB2 + ER_ + seg*4] = pk;
    }
}

// ---------------- GEMM2: out = w2x . hg^T, one LDS stage + barrier ----------
// grid 2304 = 8 xcd * (8 b * (6 pt * 6 nt)); BM=128 p, BN=64 n, K=288.
#define HGS 296   // u16 LDS stride (148 dw -> 2-way aliasing, free)
__global__ __launch_bounds__(512, 6) void gemm2_kernel(
        const unsigned short* __restrict__ hg, const unsigned short* __restrict__ w2x,
        float* __restrict__ out) {
    __shared__ __align__(16) char smem[64 * HGS * 2];      // 37888 B
    unsigned short* hgL = (unsigned short*)smem;           // [64][296]
    const int bid = blockIdx.x;
    const int xcd = bid & 7;
    const int idx = bid >> 3;            // 0..287
    const int b   = (xcd << 3) + idx / 36;
    const int rem = idx % 36;
    const int p0  = (rem / 6) * 128;
    const int n0  = (rem % 6) * 64;

    const int tid  = threadIdx.x;
    const int lane = tid & 63;
    const int wave = tid >> 6;
    const int l15  = lane & 15;
    const int kgrp = lane >> 4;

    // stage hg tile [64][288] -> LDS (16B chunks, 36 per row)
    const unsigned short* hgb = hg + ((size_t)b * HGROWS + n0) * KB2;
    #pragma unroll
    for (int it = 0; it < 5; ++it) {
        int c = tid + it*512;
        if (c < 64*36) {
            int row = c / 36, col = c % 36;
            *(u16x8*)&hgL[(size_t)row*HGS + col*8] =
                *(const u16x8*)&hgb[(size_t)row*KB2 + col*8];
        }
    }
    __syncthreads();

    // K-loop: wave owns 16 p-rows; A-frags from L2-hot w2x, B-frags from LDS
    int prow = p0 + wave*16 + l15; if (prow > P_-1) prow = P_-1;
    const unsigned short* ap = w2x + (size_t)prow*KB2;
    f32x4 o[4];
    #pragma unroll
    for (int j = 0; j < 4; ++j) o[j] = (f32x4){0.f,0.f,0.f,0.f};
    #pragma unroll
    for (int ks = 0; ks < 9; ++ks) {
        bf16x8 afr = *(const bf16x8*)&ap[ks*32 + kgrp*8];
        #pragma unroll
        for (int fn = 0; fn < 4; ++fn) {
            bf16x8 bfr = *(const bf16x8*)&hgL[(size_t)(fn*16 + l15)*HGS + ks*32 + kgrp*8];
            o[fn] = __builtin_amdgcn_mfma_f32_16x16x32_bf16(afr, bfr, o[fn], 0, 0, 0);
        }
    }
    __syncthreads();   // all waves done reading hgL; patch may overwrite

    // patch-transpose: D rows p_loc = kgrp*4+j, cols n_loc = fn*16+l15
    float* patch = (float*)smem + wave * 1088;   // [16][68] f32 = 4352 B
    #pragma unroll
    for (int fn = 0; fn < 4; ++fn)
        #pragma unroll
        for (int j = 0; j < 4; ++j)
            patch[(kgrp*4 + j)*68 + fn*16 + l15] = o[fn][j];
    const int pw0 = p0 + wave*16;
    #pragma unroll
    for (int pass = 0; pass < 4; ++pass) {
        int ploc = pass*4 + kgrp;
        f32x4 v = *(const f32x4*)&patch[ploc*68 + l15*4];
        int p = pw0 + ploc;
        int n = n0 + l15*4;
        if (p < P_) {
            float* orow = out + ((size_t)b*P_ + p)*N_;
            if (n + 3 < N_) {
                *(f32x4*)&orow[n] = v;
            } else {
                #pragma unroll
                for (int j = 0; j < 4; ++j)
                    if (n + j < N_) orow[n + j] = v[j];
            }
        }
    }
}

extern "C" void kernel_launch(void* const* d_in, const int* in_sizes, int n_in,
                              void* d_out, int out_size, void* d_ws, size_t ws_size,
                              hipStream_t stream) {
    const float* x     = (const float*)d_in[0];
    const float* ident = (const float*)d_in[1];
    const float* rw1   = (const float*)d_in[2];
    const float* rb1   = (const float*)d_in[3];
    const float* rw2   = (const float*)d_in[4];
    const float* rb2   = (const float*)d_in[5];
    const float* w1    = (const float*)d_in[6];
    const float* w2    = (const float*)d_in[7];
    const float* bias  = (const float*)d_in[8];
    float* out = (float*)d_out;
    float* ws  = (float*)d_ws;

    float* gate = ws + OFF_GATE;
    float* cs1  = ws + OFF_CS1;
    unsigned short* w1k = (unsigned short*)(ws + OFF_W1K);
    unsigned short* w2x = (unsigned short*)(ws + OFF_W2X);
    unsigned short* hg  = (unsigned short*)(ws + OFF_HG);

    prep_kernel<<<856 + N_, 512, 0, stream>>>(w1, w2, bias, ident, rw1, rb1,
                                              rw2, rb2, w1k, w2x, cs1, gate);
    gemm1_kernel<<<dim3(768), 512, 0, stream>>>(x, w1k, gate, cs1, hg);
    gemm2_kernel<<<dim3(2304), 512, 0, stream>>>(hg, w2x, out);
}